// Round 1
// baseline (354.744 us; speedup 1.0000x reference)
//
#include <hip/hip_runtime.h>
#include <hip/hip_bf16.h>

#define E_ 8
#define D_ 1024
#define F_ 4096
#define S_ 2048
#define B_ 2
#define T_ 4096
#define LN_EPS 1e-5f

typedef __attribute__((ext_vector_type(8))) short short8;
typedef __attribute__((ext_vector_type(4))) float f32x4;

__device__ __forceinline__ unsigned short f2bf(float f) {
  __hip_bfloat16 h = __float2bfloat16(f);
  return *reinterpret_cast<unsigned short*>(&h);
}

__device__ __forceinline__ void gload_lds16(const void* g, void* l) {
  __builtin_amdgcn_global_load_lds((const __attribute__((address_space(1))) void*)g,
                                   (__attribute__((address_space(3))) void*)l,
                                   16, 0, 0);
}

// ---------------- gating: 1 wave per token ----------------
__global__ __launch_bounds__(256) void gate_kernel(const float* __restrict__ x,
    const float* __restrict__ cent, int* __restrict__ assign_, int* __restrict__ counts) {
  int token = blockIdx.x * 4 + (threadIdx.x >> 6);
  int lane = threadIdx.x & 63;
  int s = token & (S_ - 1);
  int b = token >> 11;
  const float* xr = x + ((size_t)s * B_ + b) * D_;
  float acc[E_];
#pragma unroll
  for (int e = 0; e < E_; ++e) acc[e] = 0.f;
#pragma unroll
  for (int c = 0; c < 4; ++c) {
    f32x4 xv = *(const f32x4*)(xr + c * 256 + lane * 4);
#pragma unroll
    for (int e = 0; e < E_; ++e) {
      f32x4 cv = *(const f32x4*)(cent + e * D_ + c * 256 + lane * 4);
      acc[e] += xv.x * cv.x + xv.y * cv.y + xv.z * cv.z + xv.w * cv.w;
    }
  }
#pragma unroll
  for (int off = 32; off > 0; off >>= 1) {
#pragma unroll
    for (int e = 0; e < E_; ++e) acc[e] += __shfl_down(acc[e], off);
  }
  if (lane == 0) {
    int best = 0; float bv = acc[0];
#pragma unroll
    for (int e = 1; e < E_; ++e) if (acc[e] > bv) { bv = acc[e]; best = e; }
    assign_[token] = best;
    atomicAdd(&counts[best], 1);
  }
}

__global__ void prefix_kernel(const int* __restrict__ counts, int* __restrict__ offs,
                              int* __restrict__ cursor) {
  if (threadIdx.x == 0) {
    int s = 0;
    for (int e = 0; e < E_; ++e) { offs[e] = s; cursor[e] = s; s += counts[e]; }
    offs[E_] = s;
  }
}

// ---------------- LN + bucket-scatter: 1 wave per token ----------------
__global__ __launch_bounds__(256) void ln_scatter_kernel(const float* __restrict__ x,
    const float* __restrict__ g_, const float* __restrict__ bb_,
    const int* __restrict__ assign_, int* __restrict__ cursor,
    int* __restrict__ perm, unsigned short* __restrict__ Xb) {
  int token = blockIdx.x * 4 + (threadIdx.x >> 6);
  int lane = threadIdx.x & 63;
  int s = token & (S_ - 1), b = token >> 11;
  const float* xr = x + ((size_t)s * B_ + b) * D_;
  float v[16];
  float sum = 0.f, sq = 0.f;
#pragma unroll
  for (int c = 0; c < 4; ++c) {
    f32x4 xv = *(const f32x4*)(xr + c * 256 + lane * 4);
    v[c * 4 + 0] = xv.x; v[c * 4 + 1] = xv.y; v[c * 4 + 2] = xv.z; v[c * 4 + 3] = xv.w;
    sum += xv.x + xv.y + xv.z + xv.w;
    sq += xv.x * xv.x + xv.y * xv.y + xv.z * xv.z + xv.w * xv.w;
  }
#pragma unroll
  for (int off = 32; off > 0; off >>= 1) {
    sum += __shfl_down(sum, off);
    sq += __shfl_down(sq, off);
  }
  sum = __shfl(sum, 0); sq = __shfl(sq, 0);
  float mu = sum * (1.f / D_);
  float var = sq * (1.f / D_) - mu * mu;
  float rstd = rsqrtf(var + LN_EPS);
  int e = assign_[token];
  int slot = 0;
  if (lane == 0) { slot = atomicAdd(&cursor[e], 1); perm[slot] = token; }
  slot = __shfl(slot, 0);
  unsigned short* dst = Xb + (size_t)slot * D_;
#pragma unroll
  for (int c = 0; c < 4; ++c) {
    int d = c * 256 + lane * 4;
    f32x4 gv = *(const f32x4*)(g_ + e * D_ + d);
    f32x4 bv = *(const f32x4*)(bb_ + e * D_ + d);
    ushort4 o;
    o.x = f2bf((v[c * 4 + 0] - mu) * rstd * gv.x + bv.x);
    o.y = f2bf((v[c * 4 + 1] - mu) * rstd * gv.y + bv.y);
    o.z = f2bf((v[c * 4 + 2] - mu) * rstd * gv.z + bv.z);
    o.w = f2bf((v[c * 4 + 3] - mu) * rstd * gv.w + bv.w);
    *(ushort4*)(dst + d) = o;
  }
}

// ---------------- transpose + fp32->bf16: in [E][R][C] -> out [E][C][R] ----------------
__global__ __launch_bounds__(256) void transpose_bf16_kernel(const float* __restrict__ in,
    unsigned short* __restrict__ out, int R, int C) {
  __shared__ float tile[64][65];
  const float* src = in + (size_t)blockIdx.z * R * C;
  unsigned short* dst = out + (size_t)blockIdx.z * R * C;
  int c0 = blockIdx.x * 64, r0 = blockIdx.y * 64;
  int tid = threadIdx.x;
#pragma unroll
  for (int i = 0; i < 4; ++i) {
    int u = i * 256 + tid;
    int rr = u >> 4, c4 = (u & 15) * 4;
    f32x4 vv = *(const f32x4*)(src + (size_t)(r0 + rr) * C + c0 + c4);
    tile[rr][c4 + 0] = vv.x; tile[rr][c4 + 1] = vv.y;
    tile[rr][c4 + 2] = vv.z; tile[rr][c4 + 3] = vv.w;
  }
  __syncthreads();
#pragma unroll
  for (int i = 0; i < 4; ++i) {
    int u = i * 256 + tid;
    int orow = u >> 4;
    int oc4 = (u & 15) * 4;
    ushort4 o;
    o.x = f2bf(tile[oc4 + 0][orow]);
    o.y = f2bf(tile[oc4 + 1][orow]);
    o.z = f2bf(tile[oc4 + 2][orow]);
    o.w = f2bf(tile[oc4 + 3][orow]);
    *(ushort4*)(dst + (size_t)(c0 + orow) * R + r0 + oc4) = o;
  }
}

// ---------------- grouped GEMM: A[rows][K] bf16 x Bt[E][N][K] bf16 ----------------
// MODE 0: H = relu(A*W1 + b1) -> bf16   MODE 1: out = resid + A*W2 + b2 -> f32
template <int K, int N, int MODE>
__global__ __launch_bounds__(256) void moe_gemm_kernel(
    const unsigned short* __restrict__ A,
    const unsigned short* __restrict__ Bt,
    const float* __restrict__ bias,
    const int* __restrict__ offs,
    const int* __restrict__ perm,
    const float* __restrict__ resid,
    void* __restrict__ outp) {
  const int e = blockIdx.z;
  const int off = offs[e];
  const int cnt = offs[e + 1] - off;
  const int m0 = blockIdx.y * 128;
  if (m0 >= cnt) return;
  const int n0 = blockIdx.x * 128;
  const int tid = threadIdx.x;
  const int lane = tid & 63;
  const int wave = tid >> 6;

  __shared__ __align__(16) unsigned short lA[128 * 32];
  __shared__ __align__(16) unsigned short lB[128 * 32];

  const int r0 = tid >> 2;   // 0..63
  const int kc = tid & 3;    // 16B chunk within BK=32
  const int ar0 = off + min(m0 + r0, cnt - 1);
  const int ar1 = off + min(m0 + 64 + r0, cnt - 1);
  const unsigned short* aptr0 = A + (size_t)ar0 * K + kc * 8;
  const unsigned short* aptr1 = A + (size_t)ar1 * K + kc * 8;
  const unsigned short* bbase = Bt + (size_t)e * N * K + (size_t)n0 * K;
  const unsigned short* bptr0 = bbase + (size_t)r0 * K + kc * 8;
  const unsigned short* bptr1 = bbase + (size_t)(64 + r0) * K + kc * 8;

  unsigned short* lA0 = lA + wave * 512;
  unsigned short* lA1 = lA + 2048 + wave * 512;
  unsigned short* lB0 = lB + wave * 512;
  unsigned short* lB1 = lB + 2048 + wave * 512;

  f32x4 acc[4][4] = {};

  const int wr = (wave >> 1) * 64;
  const int wc = (wave & 1) * 64;
  const int fr = lane & 15;
  const int kq = (lane >> 4) * 8;

  for (int k0 = 0; k0 < K; k0 += 32) {
    __syncthreads();
    gload_lds16(aptr0 + k0, lA0);
    gload_lds16(aptr1 + k0, lA1);
    gload_lds16(bptr0 + k0, lB0);
    gload_lds16(bptr1 + k0, lB1);
    __syncthreads();
    short8 af[4], bf[4];
#pragma unroll
    for (int m = 0; m < 4; ++m)
      af[m] = *(const short8*)&lA[(wr + m * 16 + fr) * 32 + kq];
#pragma unroll
    for (int n = 0; n < 4; ++n)
      bf[n] = *(const short8*)&lB[(wc + n * 16 + fr) * 32 + kq];
#pragma unroll
    for (int m = 0; m < 4; ++m) {
#pragma unroll
      for (int n = 0; n < 4; ++n)
        acc[m][n] = __builtin_amdgcn_mfma_f32_16x16x32_bf16(af[m], bf[n], acc[m][n], 0, 0, 0);
    }
  }

  const int cr = (lane >> 4) * 4;
  if (MODE == 0) {
    unsigned short* H = (unsigned short*)outp;
#pragma unroll
    for (int m = 0; m < 4; ++m) {
#pragma unroll
      for (int j = 0; j < 4; ++j) {
        int rowl = wr + m * 16 + cr + j;
        int row = m0 + rowl;
        if (row < cnt) {
          size_t base = (size_t)(off + row) * N;
#pragma unroll
          for (int n = 0; n < 4; ++n) {
            int f = n0 + wc + n * 16 + fr;
            float hv = acc[m][n][j] + bias[e * N + f];
            hv = fmaxf(hv, 0.f);
            H[base + f] = f2bf(hv);
          }
        }
      }
    }
  } else {
    float* Out = (float*)outp;
#pragma unroll
    for (int m = 0; m < 4; ++m) {
#pragma unroll
      for (int j = 0; j < 4; ++j) {
        int rowl = wr + m * 16 + cr + j;
        int row = m0 + rowl;
        if (row < cnt) {
          int token = perm[off + row];
          int s = token & (S_ - 1), b = token >> 11;
          size_t base = ((size_t)s * B_ + b) * (size_t)D_;
#pragma unroll
          for (int n = 0; n < 4; ++n) {
            int d = n0 + wc + n * 16 + fr;
            Out[base + d] = resid[base + d] + acc[m][n][j] + bias[e * N + d];
          }
        }
      }
    }
  }
}

extern "C" void kernel_launch(void* const* d_in, const int* in_sizes, int n_in,
                              void* d_out, int out_size, void* d_ws, size_t ws_size,
                              hipStream_t stream) {
  const float* x    = (const float*)d_in[0];
  const float* cent = (const float*)d_in[1];
  const float* lng  = (const float*)d_in[2];
  const float* lnb  = (const float*)d_in[3];
  const float* W1   = (const float*)d_in[4];
  const float* b1   = (const float*)d_in[5];
  const float* W2   = (const float*)d_in[6];
  const float* b2   = (const float*)d_in[7];
  float* out = (float*)d_out;

  char* ws = (char*)d_ws;
  int* counts  = (int*)(ws + 0);          // 8 ints
  int* offs    = (int*)(ws + 64);         // 9 ints
  int* cursor  = (int*)(ws + 128);        // 8 ints
  int* perm    = (int*)(ws + 256);        // T ints
  int* assign_ = (int*)(ws + 256 + 4 * T_);
  unsigned short* Xb = (unsigned short*)(ws + ((size_t)1 << 16));   // [T][D] bf16, 8MB
  unsigned short* H  = (unsigned short*)(ws + ((size_t)1 << 24));   // [T][F] bf16, 32MB
  unsigned short* WT = (unsigned short*)(ws + ((size_t)3 << 24));   // [E][N][K] bf16, 64MB

  if (ws_size < ((size_t)7 << 24)) return;  // need 112MB scratch

  hipMemsetAsync(counts, 0, 64, stream);
  // W1 [E][D][F] -> WT [E][F][D] bf16
  transpose_bf16_kernel<<<dim3(F_ / 64, D_ / 64, E_), 256, 0, stream>>>(W1, WT, D_, F_);
  gate_kernel<<<T_ / 4, 256, 0, stream>>>(x, cent, assign_, counts);
  prefix_kernel<<<1, 64, 0, stream>>>(counts, offs, cursor);
  ln_scatter_kernel<<<T_ / 4, 256, 0, stream>>>(x, lng, lnb, assign_, cursor, perm, Xb);
  // FF1: H = relu(Xb * W1 + b1)
  moe_gemm_kernel<D_, F_, 0><<<dim3(F_ / 128, T_ / 128, E_), 256, 0, stream>>>(
      Xb, WT, b1, offs, nullptr, nullptr, (void*)H);
  // W2 [E][F][D] -> WT [E][D][F] bf16
  transpose_bf16_kernel<<<dim3(D_ / 64, F_ / 64, E_), 256, 0, stream>>>(W2, WT, F_, D_);
  // FF2: out = x + H * W2 + b2
  moe_gemm_kernel<F_, D_, 1><<<dim3(D_ / 128, T_ / 128, E_), 256, 0, stream>>>(
      H, WT, b2, offs, perm, x, (void*)out);
}

// Round 2
// 348.227 us; speedup vs baseline: 1.0187x; 1.0187x over previous
//
#include <hip/hip_runtime.h>
#include <hip/hip_bf16.h>

#define E_ 8
#define D_ 1024
#define F_ 4096
#define S_ 2048
#define B_ 2
#define T_ 4096
#define LN_EPS 1e-5f
#define MAXTAB 40

typedef __attribute__((ext_vector_type(8))) short short8;
typedef __attribute__((ext_vector_type(4))) float f32x4;

__device__ __forceinline__ unsigned short f2bf(float f) {
  __hip_bfloat16 h = __float2bfloat16(f);
  return *reinterpret_cast<unsigned short*>(&h);
}

__device__ __forceinline__ void gload_lds16(const void* g, void* l) {
  __builtin_amdgcn_global_load_lds((const __attribute__((address_space(1))) void*)g,
                                   (__attribute__((address_space(3))) void*)l,
                                   16, 0, 0);
}

// ---------------- gating: 1 wave per token ----------------
__global__ __launch_bounds__(256) void gate_kernel(const float* __restrict__ x,
    const float* __restrict__ cent, int* __restrict__ assign_, int* __restrict__ counts) {
  int token = blockIdx.x * 4 + (threadIdx.x >> 6);
  int lane = threadIdx.x & 63;
  int s = token & (S_ - 1);
  int b = token >> 11;
  const float* xr = x + ((size_t)s * B_ + b) * D_;
  float acc[E_];
#pragma unroll
  for (int e = 0; e < E_; ++e) acc[e] = 0.f;
#pragma unroll
  for (int c = 0; c < 4; ++c) {
    f32x4 xv = *(const f32x4*)(xr + c * 256 + lane * 4);
#pragma unroll
    for (int e = 0; e < E_; ++e) {
      f32x4 cv = *(const f32x4*)(cent + e * D_ + c * 256 + lane * 4);
      acc[e] += xv.x * cv.x + xv.y * cv.y + xv.z * cv.z + xv.w * cv.w;
    }
  }
#pragma unroll
  for (int off = 32; off > 0; off >>= 1) {
#pragma unroll
    for (int e = 0; e < E_; ++e) acc[e] += __shfl_down(acc[e], off);
  }
  if (lane == 0) {
    int best = 0; float bv = acc[0];
#pragma unroll
    for (int e = 1; e < E_; ++e) if (acc[e] > bv) { bv = acc[e]; best = e; }
    assign_[token] = best;
    atomicAdd(&counts[best], 1);
  }
}

// ---------------- prefix + m-block schedule table ----------------
__global__ void prefix_kernel(const int* __restrict__ counts, int* __restrict__ offs,
                              int* __restrict__ cursor, int* __restrict__ tab) {
  if (threadIdx.x == 0) {
    int s = 0, t = 0;
    for (int e = 0; e < E_; ++e) {
      offs[e] = s; cursor[e] = s;
      int nb = (counts[e] + 127) >> 7;
      for (int m = 0; m < nb; ++m) tab[t++] = (e << 16) | m;
      s += counts[e];
    }
    offs[E_] = s;
    for (; t < MAXTAB; ++t) tab[t] = -1;
  }
}

// ---------------- LN + bucket-scatter + out-init (x + b2[e]) ----------------
__global__ __launch_bounds__(256) void ln_scatter_kernel(const float* __restrict__ x,
    const float* __restrict__ g_, const float* __restrict__ bb_,
    const float* __restrict__ b2_,
    const int* __restrict__ assign_, int* __restrict__ cursor,
    int* __restrict__ perm, unsigned short* __restrict__ Xb,
    float* __restrict__ outp) {
  int token = blockIdx.x * 4 + (threadIdx.x >> 6);
  int lane = threadIdx.x & 63;
  int s = token & (S_ - 1), b = token >> 11;
  const float* xr = x + ((size_t)s * B_ + b) * D_;
  float* orow = outp + ((size_t)s * B_ + b) * D_;
  float v[16];
  float sum = 0.f, sq = 0.f;
#pragma unroll
  for (int c = 0; c < 4; ++c) {
    f32x4 xv = *(const f32x4*)(xr + c * 256 + lane * 4);
    v[c * 4 + 0] = xv.x; v[c * 4 + 1] = xv.y; v[c * 4 + 2] = xv.z; v[c * 4 + 3] = xv.w;
    sum += xv.x + xv.y + xv.z + xv.w;
    sq += xv.x * xv.x + xv.y * xv.y + xv.z * xv.z + xv.w * xv.w;
  }
#pragma unroll
  for (int off = 32; off > 0; off >>= 1) {
    sum += __shfl_down(sum, off);
    sq += __shfl_down(sq, off);
  }
  sum = __shfl(sum, 0); sq = __shfl(sq, 0);
  float mu = sum * (1.f / D_);
  float var = sq * (1.f / D_) - mu * mu;
  float rstd = rsqrtf(var + LN_EPS);
  int e = assign_[token];
  int slot = 0;
  if (lane == 0) { slot = atomicAdd(&cursor[e], 1); perm[slot] = token; }
  slot = __shfl(slot, 0);
  unsigned short* dst = Xb + (size_t)slot * D_;
#pragma unroll
  for (int c = 0; c < 4; ++c) {
    int d = c * 256 + lane * 4;
    f32x4 gv = *(const f32x4*)(g_ + e * D_ + d);
    f32x4 bv = *(const f32x4*)(bb_ + e * D_ + d);
    f32x4 b2v = *(const f32x4*)(b2_ + e * D_ + d);
    ushort4 o;
    o.x = f2bf((v[c * 4 + 0] - mu) * rstd * gv.x + bv.x);
    o.y = f2bf((v[c * 4 + 1] - mu) * rstd * gv.y + bv.y);
    o.z = f2bf((v[c * 4 + 2] - mu) * rstd * gv.z + bv.z);
    o.w = f2bf((v[c * 4 + 3] - mu) * rstd * gv.w + bv.w);
    *(ushort4*)(dst + d) = o;
    f32x4 oi;
    oi.x = v[c * 4 + 0] + b2v.x; oi.y = v[c * 4 + 1] + b2v.y;
    oi.z = v[c * 4 + 2] + b2v.z; oi.w = v[c * 4 + 3] + b2v.w;
    *(f32x4*)(orow + d) = oi;
  }
}

// ---------------- grouped GEMM: A[rows][K] bf16 x W[E][K][N] fp32 (cvt in-kernel) ----
// MODE 0: H = relu(A*W1 + b1) -> bf16     MODE 1: atomicAdd into out (split-K)
template <int K, int N, int MODE, int KSPLIT>
__global__ __launch_bounds__(256) void moe_gemm_kernel(
    const unsigned short* __restrict__ A,
    const float* __restrict__ W,
    const float* __restrict__ bias,
    const int* __restrict__ offs,
    const int* __restrict__ tab,
    const int* __restrict__ perm,
    void* __restrict__ outp) {
  const int tentry = tab[blockIdx.y];
  if (tentry < 0) return;
  const int e = tentry >> 16;
  const int m0 = (tentry & 0xffff) << 7;
  const int off = offs[e];
  const int cnt = offs[e + 1] - off;
  const int n0 = blockIdx.x * 128;
  const int kstart = blockIdx.z * (K / KSPLIT);
  constexpr int NSTEP = (K / KSPLIT) / 32;

  const int tid = threadIdx.x;
  const int lane = tid & 63;
  const int wave = tid >> 6;

  __shared__ __align__(16) unsigned short lA[4096];  // [q 0..3][row 0..127][8]
  __shared__ __align__(16) unsigned short lB[4096];  // [q 0..3][col 0..127][8]

  // A staging (global_load_lds, pre-swizzled source addresses)
  const int ar = tid & 127;
  const int aq0 = tid >> 7;  // 0..1; round1 uses +2
  const int arow = off + min(m0 + ar, cnt - 1);
  const unsigned short* ap = A + (size_t)arow * K + kstart;
  unsigned short* ldst0 = lA + (0 * 256 + wave * 64) * 8;
  unsigned short* ldst1 = lA + (1 * 256 + wave * 64) * 8;

  // B staging (fp32 -> regs -> cvt -> LDS). wave = k-oct q, thread = col pair.
  const int bq = wave;
  const int bn = (tid & 63) * 2;
  const float* wp = W + (size_t)e * K * N + (size_t)(kstart + bq * 8) * N + n0 + bn;
  unsigned short* bdst = lB + bq * 1024 + bn * 8;

  f32x4 acc[4][4] = {};
  const int wr = (wave >> 1) * 64;
  const int wc = (wave & 1) * 64;
  const int fr = lane & 15;
  const int fq = lane >> 4;
  const unsigned short* fA = lA + fq * 1024 + (wr + fr) * 8;
  const unsigned short* fB = lB + fq * 1024 + (wc + fr) * 8;

  float2 br[8];
#pragma unroll
  for (int j = 0; j < 8; ++j) br[j] = *(const float2*)(wp + (size_t)j * N);

  for (int s = 0; s < NSTEP; ++s) {
    __syncthreads();
    // pack + write B tile (this step's regs)
    short8 c0, c1;
#pragma unroll
    for (int j = 0; j < 8; ++j) {
      c0[j] = (short)f2bf(br[j].x);
      c1[j] = (short)f2bf(br[j].y);
    }
    *(short8*)(bdst) = c0;
    *(short8*)(bdst + 8) = c1;
    // A tile via async global->LDS
    gload_lds16(ap + s * 32 + aq0 * 8, ldst0);
    gload_lds16(ap + s * 32 + (aq0 + 2) * 8, ldst1);
    __syncthreads();
    short8 af[4], bf[4];
#pragma unroll
    for (int m = 0; m < 4; ++m) af[m] = *(const short8*)(fA + m * 128);
#pragma unroll
    for (int n = 0; n < 4; ++n) bf[n] = *(const short8*)(fB + n * 128);
    // prefetch next B tile into regs; latency hides under MFMA
    if (s + 1 < NSTEP) {
      const float* wp2 = wp + (size_t)(s + 1) * 32 * N;
#pragma unroll
      for (int j = 0; j < 8; ++j) br[j] = *(const float2*)(wp2 + (size_t)j * N);
    }
#pragma unroll
    for (int m = 0; m < 4; ++m) {
#pragma unroll
      for (int n = 0; n < 4; ++n)
        acc[m][n] = __builtin_amdgcn_mfma_f32_16x16x32_bf16(af[m], bf[n], acc[m][n], 0, 0, 0);
    }
  }

  if (MODE == 0) {
    unsigned short* Hout = (unsigned short*)outp;
    float bv[4];
#pragma unroll
    for (int n = 0; n < 4; ++n) bv[n] = bias[e * N + n0 + wc + n * 16 + fr];
#pragma unroll
    for (int m = 0; m < 4; ++m) {
#pragma unroll
      for (int j = 0; j < 4; ++j) {
        int rg = m0 + wr + m * 16 + fq * 4 + j;
        if (rg < cnt) {
          size_t base = (size_t)(off + rg) * N;
#pragma unroll
          for (int n = 0; n < 4; ++n) {
            float hv = acc[m][n][j] + bv[n];
            hv = fmaxf(hv, 0.f);
            Hout[base + n0 + wc + n * 16 + fr] = f2bf(hv);
          }
        }
      }
    }
  } else {
    float* Out = (float*)outp;
#pragma unroll
    for (int m = 0; m < 4; ++m) {
#pragma unroll
      for (int j = 0; j < 4; ++j) {
        int rg = m0 + wr + m * 16 + fq * 4 + j;
        if (rg < cnt) {
          int token = perm[off + rg];
          size_t base = ((size_t)(token & (S_ - 1)) * B_ + (token >> 11)) * (size_t)D_;
#pragma unroll
          for (int n = 0; n < 4; ++n)
            atomicAdd(&Out[base + n0 + wc + n * 16 + fr], acc[m][n][j]);
        }
      }
    }
  }
}

extern "C" void kernel_launch(void* const* d_in, const int* in_sizes, int n_in,
                              void* d_out, int out_size, void* d_ws, size_t ws_size,
                              hipStream_t stream) {
  const float* x    = (const float*)d_in[0];
  const float* cent = (const float*)d_in[1];
  const float* lng  = (const float*)d_in[2];
  const float* lnb  = (const float*)d_in[3];
  const float* W1   = (const float*)d_in[4];
  const float* b1   = (const float*)d_in[5];
  const float* W2   = (const float*)d_in[6];
  const float* b2   = (const float*)d_in[7];
  float* out = (float*)d_out;

  char* ws = (char*)d_ws;
  int* counts  = (int*)(ws + 0);
  int* offs    = (int*)(ws + 64);
  int* cursor  = (int*)(ws + 128);
  int* tab     = (int*)(ws + 256);
  int* perm    = (int*)(ws + 4096);
  int* assign_ = (int*)(ws + 4096 + 4 * T_);
  unsigned short* Xb = (unsigned short*)(ws + ((size_t)1 << 16));  // [T][D] bf16
  unsigned short* H  = (unsigned short*)(ws + ((size_t)1 << 24));  // [T][F] bf16

  if (ws_size < ((size_t)1 << 26)) return;  // need 64MB scratch

  hipMemsetAsync(counts, 0, 64, stream);
  gate_kernel<<<T_ / 4, 256, 0, stream>>>(x, cent, assign_, counts);
  prefix_kernel<<<1, 64, 0, stream>>>(counts, offs, cursor, tab);
  ln_scatter_kernel<<<T_ / 4, 256, 0, stream>>>(x, lng, lnb, b2, assign_, cursor, perm, Xb, out);
  // FF1: H = relu(Xb * W1 + b1)
  moe_gemm_kernel<D_, F_, 0, 1><<<dim3(F_ / 128, MAXTAB, 1), 256, 0, stream>>>(
      Xb, W1, b1, offs, tab, perm, (void*)H);
  // FF2: out += H * W2 (split-K=2; out pre-initialized with x + b2)
  moe_gemm_kernel<F_, D_, 1, 2><<<dim3(D_ / 128, MAXTAB, 2), 256, 0, stream>>>(
      H, W2, nullptr, offs, tab, perm, (void*)out);
}

// Round 3
// 285.493 us; speedup vs baseline: 1.2426x; 1.2197x over previous
//
#include <hip/hip_runtime.h>
#include <hip/hip_bf16.h>

#define E_ 8
#define D_ 1024
#define F_ 4096
#define S_ 2048
#define B_ 2
#define T_ 4096
#define CAP 1024
#define LN_EPS 1e-5f
#define MAXTAB 40

typedef __attribute__((ext_vector_type(8))) short short8;
typedef __attribute__((ext_vector_type(4))) float f32x4;

__device__ __forceinline__ unsigned short f2bf(float f) {
  __hip_bfloat16 h = __float2bfloat16(f);
  return *reinterpret_cast<unsigned short*>(&h);
}

__device__ __forceinline__ void gload_lds16(const void* g, void* l) {
  __builtin_amdgcn_global_load_lds((const __attribute__((address_space(1))) void*)g,
                                   (__attribute__((address_space(3))) void*)l,
                                   16, 0, 0);
}

// ---------- fused gating + LN + bucket scatter + out init (x + b2[e]) ----------
__global__ __launch_bounds__(256) void gate_ln_kernel(
    const float* __restrict__ x, const float* __restrict__ cent,
    const float* __restrict__ g_, const float* __restrict__ bb_,
    const float* __restrict__ b2_,
    int* __restrict__ counts, int* __restrict__ perm,
    unsigned short* __restrict__ Xb, float* __restrict__ outp) {
  int token = blockIdx.x * 4 + (threadIdx.x >> 6);
  int lane = threadIdx.x & 63;
  int s = token & (S_ - 1), b = token >> 11;
  const float* xr = x + ((size_t)s * B_ + b) * D_;
  float* orow = outp + ((size_t)s * B_ + b) * D_;

  float v[16];
  float acc[E_];
#pragma unroll
  for (int e = 0; e < E_; ++e) acc[e] = 0.f;
  float sum = 0.f, sq = 0.f;
#pragma unroll
  for (int c = 0; c < 4; ++c) {
    f32x4 xv = *(const f32x4*)(xr + c * 256 + lane * 4);
    v[c * 4 + 0] = xv.x; v[c * 4 + 1] = xv.y; v[c * 4 + 2] = xv.z; v[c * 4 + 3] = xv.w;
    sum += xv.x + xv.y + xv.z + xv.w;
    sq += xv.x * xv.x + xv.y * xv.y + xv.z * xv.z + xv.w * xv.w;
#pragma unroll
    for (int e = 0; e < E_; ++e) {
      f32x4 cv = *(const f32x4*)(cent + e * D_ + c * 256 + lane * 4);
      acc[e] += xv.x * cv.x + xv.y * cv.y + xv.z * cv.z + xv.w * cv.w;
    }
  }
#pragma unroll
  for (int off = 32; off > 0; off >>= 1) {
    sum += __shfl_down(sum, off);
    sq += __shfl_down(sq, off);
#pragma unroll
    for (int e = 0; e < E_; ++e) acc[e] += __shfl_down(acc[e], off);
  }
  int best = 0, slot = 0;
  if (lane == 0) {
    float bv = acc[0];
#pragma unroll
    for (int e = 1; e < E_; ++e) if (acc[e] > bv) { bv = acc[e]; best = e; }
    slot = atomicAdd(&counts[best], 1);
    perm[best * CAP + slot] = token;
  }
  best = __shfl(best, 0); slot = __shfl(slot, 0);
  sum = __shfl(sum, 0); sq = __shfl(sq, 0);
  float mu = sum * (1.f / D_);
  float var = sq * (1.f / D_) - mu * mu;
  float rstd = rsqrtf(var + LN_EPS);
  int e = best;
  unsigned short* dst = Xb + (size_t)(e * CAP + slot) * D_;
#pragma unroll
  for (int c = 0; c < 4; ++c) {
    int d = c * 256 + lane * 4;
    f32x4 gv = *(const f32x4*)(g_ + e * D_ + d);
    f32x4 bv = *(const f32x4*)(bb_ + e * D_ + d);
    f32x4 b2v = *(const f32x4*)(b2_ + e * D_ + d);
    ushort4 o;
    o.x = f2bf((v[c * 4 + 0] - mu) * rstd * gv.x + bv.x);
    o.y = f2bf((v[c * 4 + 1] - mu) * rstd * gv.y + bv.y);
    o.z = f2bf((v[c * 4 + 2] - mu) * rstd * gv.z + bv.z);
    o.w = f2bf((v[c * 4 + 3] - mu) * rstd * gv.w + bv.w);
    *(ushort4*)(dst + d) = o;
    f32x4 oi;
    oi.x = v[c * 4 + 0] + b2v.x; oi.y = v[c * 4 + 1] + b2v.y;
    oi.z = v[c * 4 + 2] + b2v.z; oi.w = v[c * 4 + 3] + b2v.w;
    *(f32x4*)(orow + d) = oi;
  }
}

// ---------- prefix: H-compaction offsets + m-tile schedule table ----------
__global__ void prefix_kernel(const int* __restrict__ counts, int* __restrict__ offs,
                              int* __restrict__ tab) {
  if (threadIdx.x == 0) {
    int s = 0, t = 0;
    for (int e = 0; e < E_; ++e) {
      offs[e] = s;
      int nb = (counts[e] + 127) >> 7;
      for (int m = 0; m < nb; ++m) tab[t++] = (e << 16) | m;
      s += counts[e];
    }
    offs[E_] = s;
    for (; t < MAXTAB; ++t) tab[t] = -1;
  }
}

// ---------- grouped GEMM, 2-phase double-buffered ----------
// A[rows][K] bf16 (capacity layout MODE0 / compact MODE1), W[E][K][N] fp32.
// MODE 0: H = relu(A*W1 + b1) -> bf16 compact   MODE 1: atomicAdd into out (split-K)
template <int K, int N, int MODE, int KSPLIT>
__global__ __launch_bounds__(256) void moe_gemm_kernel(
    const unsigned short* __restrict__ A,
    const float* __restrict__ W,
    const float* __restrict__ bias,
    const int* __restrict__ counts,
    const int* __restrict__ offs,
    const int* __restrict__ tab,
    const int* __restrict__ perm,
    void* __restrict__ outp) {
  const int tentry = tab[blockIdx.y];
  if (tentry < 0) return;
  const int e = tentry >> 16;
  const int m0 = (tentry & 0xffff) << 7;
  const int cnt = counts[e];
  if (m0 >= cnt) return;
  const int aoff = (MODE == 0) ? e * CAP : offs[e];
  const int hoff = offs[e];
  const int n0 = blockIdx.x * 128;
  const int kstart = blockIdx.z * (K / KSPLIT);
  constexpr int NSTEP = (K / KSPLIT) / 32;

  const int tid = threadIdx.x;
  const int lane = tid & 63;
  const int wave = tid >> 6;

  // [buf][q 0..3][row/col 0..127][8 bf16]
  __shared__ __align__(16) unsigned short lA[2][4096];
  __shared__ __align__(16) unsigned short lB[2][4096];

  // A staging: instr0 covers cell tid (q=tid>>7,row=tid&127); instr1 cell tid+256
  const int ar = tid & 127;
  const int aq = tid >> 7;  // 0..1
  const int arow = aoff + min(m0 + ar, cnt - 1);
  const unsigned short* asrc = A + (size_t)arow * K + kstart + aq * 8;

  // B staging: wave q handles k-rows q*8..q*8+7; lane covers cols {lane, lane+64}
  const float* wsrc = W + (size_t)e * K * N + (size_t)(kstart + wave * 8) * N + n0 + lane;

  f32x4 acc[4][4] = {};
  const int wr = (wave >> 1) * 64;
  const int wc = (wave & 1) * 64;
  const int fr = lane & 15;
  const int fq = lane >> 4;

  float bA[8], bB[8];
  // ---- prologue: stage tile 0 into buf 0 ----
#pragma unroll
  for (int j = 0; j < 8; ++j) { bA[j] = wsrc[(size_t)j * N]; bB[j] = wsrc[(size_t)j * N + 64]; }
  gload_lds16(asrc, (char*)&lA[0][0] + wave * 1024);
  gload_lds16(asrc + 16, (char*)&lA[0][0] + (4 + wave) * 1024);
  {
    short8 c0, c1;
#pragma unroll
    for (int j = 0; j < 8; ++j) { c0[j] = (short)f2bf(bA[j]); c1[j] = (short)f2bf(bB[j]); }
    *(short8*)&lB[0][(wave * 128 + lane) * 8] = c0;
    *(short8*)&lB[0][(wave * 128 + lane + 64) * 8] = c1;
  }
  __syncthreads();

  for (int t = 0; t < NSTEP; ++t) {
    const int cur = t & 1, nxt = cur ^ 1;
    if (t + 1 < NSTEP) {
      const float* wn = wsrc + (size_t)(t + 1) * 32 * N;
#pragma unroll
      for (int j = 0; j < 8; ++j) { bA[j] = wn[(size_t)j * N]; bB[j] = wn[(size_t)j * N + 64]; }
      const unsigned short* an = asrc + (t + 1) * 32;
      gload_lds16(an, (char*)&lA[nxt][0] + wave * 1024);
      gload_lds16(an + 16, (char*)&lA[nxt][0] + (4 + wave) * 1024);
    }
    short8 af[4], bf4[4];
#pragma unroll
    for (int m = 0; m < 4; ++m)
      af[m] = *(const short8*)&lA[cur][fq * 1024 + (wr + m * 16 + fr) * 8];
#pragma unroll
    for (int n = 0; n < 4; ++n)
      bf4[n] = *(const short8*)&lB[cur][fq * 1024 + (wc + n * 16 + fr) * 8];
#pragma unroll
    for (int m = 0; m < 4; ++m) {
#pragma unroll
      for (int n = 0; n < 4; ++n)
        acc[m][n] = __builtin_amdgcn_mfma_f32_16x16x32_bf16(af[m], bf4[n], acc[m][n], 0, 0, 0);
    }
    if (t + 1 < NSTEP) {
      short8 c0, c1;
#pragma unroll
      for (int j = 0; j < 8; ++j) { c0[j] = (short)f2bf(bA[j]); c1[j] = (short)f2bf(bB[j]); }
      *(short8*)&lB[nxt][(wave * 128 + lane) * 8] = c0;
      *(short8*)&lB[nxt][(wave * 128 + lane + 64) * 8] = c1;
    }
    __syncthreads();
  }

  if (MODE == 0) {
    unsigned short* Hout = (unsigned short*)outp;
    float bv[4];
#pragma unroll
    for (int n = 0; n < 4; ++n) bv[n] = bias[e * N + n0 + wc + n * 16 + fr];
#pragma unroll
    for (int m = 0; m < 4; ++m) {
#pragma unroll
      for (int j = 0; j < 4; ++j) {
        int rg = m0 + wr + m * 16 + fq * 4 + j;
        if (rg < cnt) {
          size_t base = (size_t)(hoff + rg) * N;
#pragma unroll
          for (int n = 0; n < 4; ++n) {
            float hv = acc[m][n][j] + bv[n];
            hv = fmaxf(hv, 0.f);
            Hout[base + n0 + wc + n * 16 + fr] = f2bf(hv);
          }
        }
      }
    }
  } else {
    float* Out = (float*)outp;
#pragma unroll
    for (int m = 0; m < 4; ++m) {
#pragma unroll
      for (int j = 0; j < 4; ++j) {
        int rg = m0 + wr + m * 16 + fq * 4 + j;
        if (rg < cnt) {
          int token = perm[e * CAP + rg];
          size_t base = ((size_t)(token & (S_ - 1)) * B_ + (token >> 11)) * (size_t)D_;
#pragma unroll
          for (int n = 0; n < 4; ++n)
            atomicAdd(&Out[base + n0 + wc + n * 16 + fr], acc[m][n][j]);
        }
      }
    }
  }
}

extern "C" void kernel_launch(void* const* d_in, const int* in_sizes, int n_in,
                              void* d_out, int out_size, void* d_ws, size_t ws_size,
                              hipStream_t stream) {
  const float* x    = (const float*)d_in[0];
  const float* cent = (const float*)d_in[1];
  const float* lng  = (const float*)d_in[2];
  const float* lnb  = (const float*)d_in[3];
  const float* W1   = (const float*)d_in[4];
  const float* b1   = (const float*)d_in[5];
  const float* W2   = (const float*)d_in[6];
  const float* b2   = (const float*)d_in[7];
  float* out = (float*)d_out;

  char* ws = (char*)d_ws;
  int* counts = (int*)(ws + 0);          // 8 ints
  int* offs   = (int*)(ws + 64);         // 9 ints
  int* tab    = (int*)(ws + 256);        // MAXTAB ints
  int* perm   = (int*)(ws + 4096);       // [E][CAP] ints, 32KB
  unsigned short* Xb = (unsigned short*)(ws + ((size_t)1 << 18)); // [E][CAP][D] bf16, 16MB
  unsigned short* H  = (unsigned short*)(ws + ((size_t)1 << 25)); // [T][F] bf16 compact, 32MB

  if (ws_size < ((size_t)1 << 26)) return;  // need 64MB scratch

  hipMemsetAsync(counts, 0, 64, stream);
  gate_ln_kernel<<<T_ / 4, 256, 0, stream>>>(x, cent, lng, lnb, b2, counts, perm, Xb, out);
  prefix_kernel<<<1, 64, 0, stream>>>(counts, offs, tab);
  // FF1: H = relu(Xb * W1 + b1)
  moe_gemm_kernel<D_, F_, 0, 1><<<dim3(F_ / 128, MAXTAB, 1), 256, 0, stream>>>(
      Xb, W1, b1, counts, offs, tab, perm, (void*)H);
  // FF2: out += H * W2 (split-K=2; out pre-initialized with x + b2)
  moe_gemm_kernel<F_, D_, 1, 2><<<dim3(D_ / 128, MAXTAB, 2), 256, 0, stream>>>(
      H, W2, nullptr, counts, offs, tab, perm, (void*)out);
}

// Round 4
// 279.033 us; speedup vs baseline: 1.2713x; 1.0232x over previous
//
#include <hip/hip_runtime.h>
#include <hip/hip_bf16.h>

#define E_ 8
#define D_ 1024
#define F_ 4096
#define S_ 2048
#define B_ 2
#define T_ 4096
#define CAP 1024
#define LN_EPS 1e-5f
#define MAXTAB 40

typedef __attribute__((ext_vector_type(8))) short short8;
typedef __attribute__((ext_vector_type(4))) float f32x4;

__device__ __forceinline__ unsigned short f2bf(float f) {
  __hip_bfloat16 h = __float2bfloat16(f);
  return *reinterpret_cast<unsigned short*>(&h);
}

// ---------- fused gating + LN + bucket scatter + out init (x + b2[e]) ----------
__global__ __launch_bounds__(256) void gate_ln_kernel(
    const float* __restrict__ x, const float* __restrict__ cent,
    const float* __restrict__ g_, const float* __restrict__ bb_,
    const float* __restrict__ b2_,
    int* __restrict__ counts, int* __restrict__ perm,
    unsigned short* __restrict__ Xb, float* __restrict__ outp) {
  int token = blockIdx.x * 4 + (threadIdx.x >> 6);
  int lane = threadIdx.x & 63;
  int s = token & (S_ - 1), b = token >> 11;
  const float* xr = x + ((size_t)s * B_ + b) * D_;
  float* orow = outp + ((size_t)s * B_ + b) * D_;

  float v[16];
  float acc[E_];
#pragma unroll
  for (int e = 0; e < E_; ++e) acc[e] = 0.f;
  float sum = 0.f, sq = 0.f;
#pragma unroll
  for (int c = 0; c < 4; ++c) {
    f32x4 xv = *(const f32x4*)(xr + c * 256 + lane * 4);
    v[c * 4 + 0] = xv.x; v[c * 4 + 1] = xv.y; v[c * 4 + 2] = xv.z; v[c * 4 + 3] = xv.w;
    sum += xv.x + xv.y + xv.z + xv.w;
    sq += xv.x * xv.x + xv.y * xv.y + xv.z * xv.z + xv.w * xv.w;
#pragma unroll
    for (int e = 0; e < E_; ++e) {
      f32x4 cv = *(const f32x4*)(cent + e * D_ + c * 256 + lane * 4);
      acc[e] += xv.x * cv.x + xv.y * cv.y + xv.z * cv.z + xv.w * cv.w;
    }
  }
#pragma unroll
  for (int off = 32; off > 0; off >>= 1) {
    sum += __shfl_down(sum, off);
    sq += __shfl_down(sq, off);
#pragma unroll
    for (int e = 0; e < E_; ++e) acc[e] += __shfl_down(acc[e], off);
  }
  int best = 0, slot = 0;
  if (lane == 0) {
    float bv = acc[0];
#pragma unroll
    for (int e = 1; e < E_; ++e) if (acc[e] > bv) { bv = acc[e]; best = e; }
    slot = atomicAdd(&counts[best], 1);
    perm[best * CAP + slot] = token;
  }
  best = __shfl(best, 0); slot = __shfl(slot, 0);
  sum = __shfl(sum, 0); sq = __shfl(sq, 0);
  float mu = sum * (1.f / D_);
  float var = sq * (1.f / D_) - mu * mu;
  float rstd = rsqrtf(var + LN_EPS);
  int e = best;
  unsigned short* dst = Xb + (size_t)(e * CAP + slot) * D_;
#pragma unroll
  for (int c = 0; c < 4; ++c) {
    int d = c * 256 + lane * 4;
    f32x4 gv = *(const f32x4*)(g_ + e * D_ + d);
    f32x4 bv = *(const f32x4*)(bb_ + e * D_ + d);
    f32x4 b2v = *(const f32x4*)(b2_ + e * D_ + d);
    ushort4 o;
    o.x = f2bf((v[c * 4 + 0] - mu) * rstd * gv.x + bv.x);
    o.y = f2bf((v[c * 4 + 1] - mu) * rstd * gv.y + bv.y);
    o.z = f2bf((v[c * 4 + 2] - mu) * rstd * gv.z + bv.z);
    o.w = f2bf((v[c * 4 + 3] - mu) * rstd * gv.w + bv.w);
    *(ushort4*)(dst + d) = o;
    f32x4 oi;
    oi.x = v[c * 4 + 0] + b2v.x; oi.y = v[c * 4 + 1] + b2v.y;
    oi.z = v[c * 4 + 2] + b2v.z; oi.w = v[c * 4 + 3] + b2v.w;
    *(f32x4*)(orow + d) = oi;
  }
}

// ---------- prefix: H-compaction offsets + m-tile schedule table ----------
__global__ void prefix_kernel(const int* __restrict__ counts, int* __restrict__ offs,
                              int* __restrict__ tab) {
  if (threadIdx.x == 0) {
    int s = 0, t = 0;
    for (int e = 0; e < E_; ++e) {
      offs[e] = s;
      int nb = (counts[e] + 127) >> 7;
      for (int m = 0; m < nb; ++m) tab[t++] = (e << 16) | m;
      s += counts[e];
    }
    offs[E_] = s;
    for (; t < MAXTAB; ++t) tab[t] = -1;
  }
}

// ---------- grouped GEMM, distance-2 software pipeline, reg-staged, no vmcnt drain ----
// A[rows][K] bf16 (capacity layout MODE0 / compact MODE1), W[E][K][N] fp32.
// MODE 0: H = relu(A*W1 + b1) -> bf16 compact   MODE 1: atomicAdd into out (split-K)
template <int K, int N, int MODE, int KSPLIT>
__global__ __launch_bounds__(256, 3) void moe_gemm_kernel(
    const unsigned short* __restrict__ A,
    const float* __restrict__ W,
    const float* __restrict__ bias,
    const int* __restrict__ counts,
    const int* __restrict__ offs,
    const int* __restrict__ tab,
    const int* __restrict__ perm,
    void* __restrict__ outp) {
  const int tentry = tab[blockIdx.y];
  if (tentry < 0) return;
  const int e = tentry >> 16;
  const int m0 = (tentry & 0xffff) << 7;
  const int cnt = counts[e];
  if (m0 >= cnt) return;
  const int aoff = (MODE == 0) ? e * CAP : offs[e];
  const int hoff = offs[e];
  const int n0 = blockIdx.x * 128;
  const int kstart = blockIdx.z * (K / KSPLIT);
  constexpr int NSTEP = (K / KSPLIT) / 32;
  static_assert(NSTEP >= 4 && (NSTEP % 2) == 0, "NSTEP must be even >= 4");

  const int tid = threadIdx.x;
  const int lane = tid & 63;
  const int wave = tid >> 6;

  // per buffer: [q 0..3][row/col 0..127][8 bf16]  (cell = q*1024 + idx*8 shorts)
  __shared__ __align__(16) unsigned short lA[2][4096];
  __shared__ __align__(16) unsigned short lB[2][4096];

  // A: thread covers cells (qa, ra) and (qa+2, ra)
  const int ra = tid & 127;
  const int qa = tid >> 7;  // 0..1
  const int arow = aoff + min(m0 + ra, cnt - 1);
  const unsigned short* asrc = A + (size_t)arow * K + kstart + qa * 8;

  // B: wave q handles k-rows q*8..q*8+7; lane covers cols {lane, lane+64}
  const float* wsrc = W + (size_t)e * K * N + (size_t)(kstart + wave * 8) * N + n0 + lane;

  f32x4 acc[4][4] = {};
  const int wr = (wave >> 1) * 64;
  const int wc = (wave & 1) * 64;
  const int fr = lane & 15;
  const int fq = lane >> 4;

  // two named register slots (tile parity): slot s holds tile t with t&1==s
  short8 pA00, pA01, pA10, pA11;
  float pBa0[8], pBb0[8], pBa1[8], pBb1[8];

  // ---- prologue: load tile0 -> slot0, tile1 -> slot1; write slot0 -> buf0 ----
  pA00 = *(const short8*)(asrc);
  pA01 = *(const short8*)(asrc + 16);
#pragma unroll
  for (int j = 0; j < 8; ++j) {
    pBa0[j] = wsrc[(size_t)j * N];
    pBb0[j] = wsrc[(size_t)j * N + 64];
  }
  pA10 = *(const short8*)(asrc + 32);
  pA11 = *(const short8*)(asrc + 48);
  {
    const float* wp_ = wsrc + (size_t)32 * N;
#pragma unroll
    for (int j = 0; j < 8; ++j) {
      pBa1[j] = wp_[(size_t)j * N];
      pBb1[j] = wp_[(size_t)j * N + 64];
    }
  }
  *(short8*)&lA[0][qa * 1024 + ra * 8] = pA00;
  *(short8*)&lA[0][(qa + 2) * 1024 + ra * 8] = pA01;
  {
    short8 c0_, c1_;
#pragma unroll
    for (int j = 0; j < 8; ++j) {
      c0_[j] = (short)f2bf(pBa0[j]);
      c1_[j] = (short)f2bf(pBb0[j]);
    }
    *(short8*)&lB[0][wave * 1024 + lane * 8] = c0_;
    *(short8*)&lB[0][wave * 1024 + (lane + 64) * 8] = c1_;
  }
  asm volatile("s_waitcnt lgkmcnt(0)" ::: "memory");
  __builtin_amdgcn_s_barrier();
  asm volatile("" ::: "memory");

#define STEP_BODY(TV, CUR, NXT)                                                     \
  {                                                                                 \
    const int tv_ = (TV);                                                           \
    if (tv_ + 2 < NSTEP) { /* load tile tv+2 into slot CUR (regs free) */           \
      const unsigned short* ap_ = asrc + (tv_ + 2) * 32;                            \
      pA##CUR##0 = *(const short8*)ap_;                                             \
      pA##CUR##1 = *(const short8*)(ap_ + 16);                                      \
      const float* wp_ = wsrc + (size_t)(tv_ + 2) * 32 * N;                         \
      _Pragma("unroll") for (int j = 0; j < 8; ++j) {                               \
        pBa##CUR[j] = wp_[(size_t)j * N];                                           \
        pBb##CUR[j] = wp_[(size_t)j * N + 64];                                      \
      }                                                                             \
    }                                                                               \
    if (tv_ + 1 < NSTEP) { /* write slot NXT (tile tv+1, loaded last step) */       \
      *(short8*)&lA[NXT][qa * 1024 + ra * 8] = pA##NXT##0;                          \
      *(short8*)&lA[NXT][(qa + 2) * 1024 + ra * 8] = pA##NXT##1;                    \
      short8 c0_, c1_;                                                              \
      _Pragma("unroll") for (int j = 0; j < 8; ++j) {                               \
        c0_[j] = (short)f2bf(pBa##NXT[j]);                                          \
        c1_[j] = (short)f2bf(pBb##NXT[j]);                                          \
      }                                                                             \
      *(short8*)&lB[NXT][wave * 1024 + lane * 8] = c0_;                             \
      *(short8*)&lB[NXT][wave * 1024 + (lane + 64) * 8] = c1_;                      \
    }                                                                               \
    short8 af_[4], bf_[4];                                                          \
    _Pragma("unroll") for (int m = 0; m < 4; ++m)                                   \
        af_[m] = *(const short8*)&lA[CUR][fq * 1024 + (wr + m * 16 + fr) * 8];      \
    _Pragma("unroll") for (int n = 0; n < 4; ++n)                                   \
        bf_[n] = *(const short8*)&lB[CUR][fq * 1024 + (wc + n * 16 + fr) * 8];      \
    __builtin_amdgcn_s_setprio(1);                                                  \
    _Pragma("unroll") for (int m = 0; m < 4; ++m)                                   \
        _Pragma("unroll") for (int n = 0; n < 4; ++n)                               \
            acc[m][n] =                                                             \
                __builtin_amdgcn_mfma_f32_16x16x32_bf16(af_[m], bf_[n],             \
                                                        acc[m][n], 0, 0, 0);        \
    __builtin_amdgcn_s_setprio(0);                                                  \
    asm volatile("s_waitcnt lgkmcnt(0)" ::: "memory");                              \
    __builtin_amdgcn_s_barrier();                                                   \
    asm volatile("" ::: "memory");                                                  \
  }

  for (int t = 0; t < NSTEP; t += 2) {
    STEP_BODY(t, 0, 1);
    STEP_BODY(t + 1, 1, 0);
  }
#undef STEP_BODY

  if (MODE == 0) {
    unsigned short* Hout = (unsigned short*)outp;
    float bv[4];
#pragma unroll
    for (int n = 0; n < 4; ++n) bv[n] = bias[e * N + n0 + wc + n * 16 + fr];
#pragma unroll
    for (int m = 0; m < 4; ++m) {
#pragma unroll
      for (int j = 0; j < 4; ++j) {
        int rg = m0 + wr + m * 16 + fq * 4 + j;
        if (rg < cnt) {
          size_t base = (size_t)(hoff + rg) * N;
#pragma unroll
          for (int n = 0; n < 4; ++n) {
            float hv = acc[m][n][j] + bv[n];
            hv = fmaxf(hv, 0.f);
            Hout[base + n0 + wc + n * 16 + fr] = f2bf(hv);
          }
        }
      }
    }
  } else {
    float* Out = (float*)outp;
#pragma unroll
    for (int m = 0; m < 4; ++m) {
#pragma unroll
      for (int j = 0; j < 4; ++j) {
        int rg = m0 + wr + m * 16 + fq * 4 + j;
        if (rg < cnt) {
          int token = perm[e * CAP + rg];
          size_t base = ((size_t)(token & (S_ - 1)) * B_ + (token >> 11)) * (size_t)D_;
#pragma unroll
          for (int n = 0; n < 4; ++n)
            atomicAdd(&Out[base + n0 + wc + n * 16 + fr], acc[m][n][j]);
        }
      }
    }
  }
}

extern "C" void kernel_launch(void* const* d_in, const int* in_sizes, int n_in,
                              void* d_out, int out_size, void* d_ws, size_t ws_size,
                              hipStream_t stream) {
  const float* x    = (const float*)d_in[0];
  const float* cent = (const float*)d_in[1];
  const float* lng  = (const float*)d_in[2];
  const float* lnb  = (const float*)d_in[3];
  const float* W1   = (const float*)d_in[4];
  const float* b1   = (const float*)d_in[5];
  const float* W2   = (const float*)d_in[6];
  const float* b2   = (const float*)d_in[7];
  float* out = (float*)d_out;

  char* ws = (char*)d_ws;
  int* counts = (int*)(ws + 0);          // 8 ints
  int* offs   = (int*)(ws + 64);         // 9 ints
  int* tab    = (int*)(ws + 256);        // MAXTAB ints
  int* perm   = (int*)(ws + 4096);       // [E][CAP] ints, 32KB
  unsigned short* Xb = (unsigned short*)(ws + ((size_t)1 << 18)); // [E][CAP][D] bf16, 16MB
  unsigned short* H  = (unsigned short*)(ws + ((size_t)1 << 25)); // [T][F] bf16 compact, 32MB

  if (ws_size < ((size_t)1 << 26)) return;  // need 64MB scratch

  hipMemsetAsync(counts, 0, 64, stream);
  gate_ln_kernel<<<T_ / 4, 256, 0, stream>>>(x, cent, lng, lnb, b2, counts, perm, Xb, out);
  prefix_kernel<<<1, 64, 0, stream>>>(counts, offs, tab);
  // FF1: H = relu(Xb * W1 + b1)
  moe_gemm_kernel<D_, F_, 0, 1><<<dim3(F_ / 128, MAXTAB, 1), 256, 0, stream>>>(
      Xb, W1, b1, counts, offs, tab, perm, (void*)H);
  // FF2: out += H * W2 (split-K=4; out pre-initialized with x + b2)
  moe_gemm_kernel<F_, D_, 1, 4><<<dim3(D_ / 128, MAXTAB, 4), 256, 0, stream>>>(
      H, W2, nullptr, counts, offs, tab, perm, (void*)out);
}